// Round 4
// baseline (510.277 us; speedup 1.0000x reference)
//
#include <hip/hip_runtime.h>

// GraphFeaturesStackPad on MI355X.
// Stage 1: bf16 MFMA fused up/gate projection + sigmoid-gate + IN-REGISTER
//          segment-sum (atomicAdd into d_out as fp32 graph_sums accumulator).
// Stage 2: fp32 in-place GEMM graph_sums @ W_func + b_func.
// d_ws usage: ntiles ints (~31 KB) for per-tile first-graph index.
//
// R6 changes vs R5 (post-mortem: drain-fix + occupancy both neutral ->
// bottleneck is the per-tile serial skeleton, not latency/wave-count):
//  - Gs LDS round-trip ELIMINATED. MFMA D-frags hold gated[node][f] in regs
//    (row = sub*16 + quad*4 + r); per-graph sums are done in-register with
//    predicated adds over the 16 static (sub,r) slots, then shfl_xor(16/32)
//    butterfly across quads, then one atomicAdd per (g,f). Removes 32
//    ds_writes + ~32 serial ds_reads per thread per tile and 33 KB LDS.
//  - barriers per tile 2 -> 1: Xs double-buffered (2x18 KB). bar_lds drains
//    each wave's own lgkm (A-frag reads complete before the barrier), so one
//    barrier between staging and MFMA is race-free across buffer reuse.
//  - keeps R5: unconditional clamped VMEM, lane-resident starts window
//    (__shfl broadcast), window pipelined one tile ahead, 768 blocks x
//    launch_bounds(256,3).
// Counter calibration from R3 bench: harness poison fills run at 6.8 TB/s;
// stage1 < 150.5 us (absent from top-5); stage1 BW floor ~38 us.

typedef __bf16 bf16_t;
typedef bf16_t bf16x8 __attribute__((ext_vector_type(8)));
typedef float  f32x4  __attribute__((ext_vector_type(4)));

#define XS_STRIDE 144   // shorts; 288 B row = 72 dwords -> 4-way banks on b128

__device__ __forceinline__ unsigned short f2bf(float f) {
  unsigned int u = __float_as_uint(f);
  u += 0x7fffu + ((u >> 16) & 1u);   // RNE
  return (unsigned short)(u >> 16);
}

// LDS-only barrier: drains this wave's LDS ops then barriers; global loads
// (vmcnt) stay in flight, so the pipelined next-tile loads overlap compute.
__device__ __forceinline__ void bar_lds() {
  asm volatile("s_waitcnt lgkmcnt(0)\n\ts_barrier" ::: "memory");
}

__global__ void tile_seg_kernel(const int* __restrict__ starts,
                                int* __restrict__ tile_seg,
                                int ntiles, int G) {
  int i = blockIdx.x * blockDim.x + threadIdx.x;
  if (i >= ntiles) return;
  int n0 = i * 64;
  int lo = 0, hi = G - 1;            // largest g with starts[g] <= n0
  while (lo < hi) {
    int mid = (lo + hi + 1) >> 1;
    if (starts[mid] <= n0) lo = mid; else hi = mid - 1;
  }
  tile_seg[i] = lo;
}

__global__ __launch_bounds__(256, 3)
void stage1_kernel(const float* __restrict__ X,
                   const float* __restrict__ Wu, const float* __restrict__ bu,
                   const float* __restrict__ Wg, const float* __restrict__ bg,
                   const int* __restrict__ starts,
                   const int* __restrict__ tile_seg,
                   float* __restrict__ gsum, int V, int G, int ntiles)
{
  __shared__ unsigned short Xs[2][64 * XS_STRIDE]; // double-buffered bf16 tile (36.9 KB)

  const int tid  = threadIdx.x;
  const int lane = tid & 63;
  const int wave = tid >> 6;          // 4 waves; wave owns f-strip [wave*32, +32)
  const int quad = lane >> 4;
  const int l15  = lane & 15;

  // Persistent B fragments (W_up / W_gate) in registers, loaded once per block.
  // B-frag layout: lane holds B[k = s*32 + quad*8 + j][n = lane&15].
  bf16x8 Bu[2][4], Bg[2][4];
  float bup[2], bgt[2];
#pragma unroll
  for (int t = 0; t < 2; ++t) {
    const int f = wave * 32 + t * 16 + l15;
    bup[t] = bu[f];
    bgt[t] = bg[f];
#pragma unroll
    for (int s = 0; s < 4; ++s) {
      const int k0 = s * 32 + quad * 8;
      union { unsigned short us[8]; bf16x8 v; } a, b;
#pragma unroll
      for (int j = 0; j < 8; ++j) {
        a.us[j] = f2bf(Wu[(k0 + j) * 128 + f]);
        b.us[j] = f2bf(Wg[(k0 + j) * 128 + f]);
      }
      Bu[t][s] = a.v;
      Bg[t][s] = b.v;
    }
  }

  f32x4 ld[8];
  int tile = blockIdx.x;

  // preload first tile's data + window (clamped, unconditional)
  int g0v, sval;
  {
    const int t0 = min(tile, ntiles - 1);
    g0v  = tile_seg[t0];
    sval = starts[min(g0v + lane, G)];
    const int n0 = t0 * 64;
#pragma unroll
    for (int i = 0; i < 8; ++i) {
      const int flat = tid + i * 256;
      const int n = min(n0 + (flat >> 5), V - 1);
      const int k = (flat & 31) << 2;
      ld[i] = *(const f32x4*)(X + (size_t)n * 128 + k);
    }
  }

  int it = 0;
  for (; tile < ntiles; tile += gridDim.x, ++it) {
    const int n0    = tile * 64;
    const int n_end = min(n0 + 64, V);
    const int g0 = g0v;     // this tile's window (pipelined last iteration)
    const int sv = sval;
    unsigned short* xb = Xs[it & 1];

    // staged regs -> LDS as packed bf16 (8B ds_write); consumes the prefetch
#pragma unroll
    for (int i = 0; i < 8; ++i) {
      const int flat = tid + i * 256;
      const int n = flat >> 5;
      const int k = (flat & 31) << 2;
      const unsigned int p0 =
          (unsigned int)f2bf(ld[i][0]) | ((unsigned int)f2bf(ld[i][1]) << 16);
      const unsigned int p1 =
          (unsigned int)f2bf(ld[i][2]) | ((unsigned int)f2bf(ld[i][3]) << 16);
      *(uint2*)&xb[n * XS_STRIDE + k] = make_uint2(p0, p1);
    }

    // issue next tile's global loads NOW (clamped, unconditional); they stay
    // in flight through the lgkm-only barrier and the MFMA/reduce phases
    const int nextc = min(tile + (int)gridDim.x, ntiles - 1);
    {
      const int m0 = nextc * 64;
#pragma unroll
      for (int i = 0; i < 8; ++i) {
        const int flat = tid + i * 256;
        const int n = min(m0 + (flat >> 5), V - 1);
        const int k = (flat & 31) << 2;
        ld[i] = *(const f32x4*)(X + (size_t)n * 128 + k);
      }
    }
    // pipeline next tile's starts window (consumed next iteration's reduce)
    g0v  = tile_seg[nextc];
    sval = starts[min(g0v + lane, G)];

    bar_lds();   // ONE barrier per tile: Xs[it&1] writes visible; each wave's
                 // previous-tile A-frag reads already drained by its own lgkm

    // ---- MFMA phase + in-register epilogue: gv[sub][t][r] ----
    float gv[4][2][4];
#pragma unroll
    for (int sub = 0; sub < 4; ++sub) {
      bf16x8 A[4];
      const int nl = sub * 16 + l15;   // A-frag: A[m=lane&15][k=quad*8+j]
#pragma unroll
      for (int s = 0; s < 4; ++s)
        A[s] = *(const bf16x8*)&xb[nl * XS_STRIDE + s * 32 + quad * 8];
#pragma unroll
      for (int t = 0; t < 2; ++t) {
        f32x4 au = {0.f, 0.f, 0.f, 0.f};
        f32x4 ag = {0.f, 0.f, 0.f, 0.f};
#pragma unroll
        for (int s = 0; s < 4; ++s) {
          au = __builtin_amdgcn_mfma_f32_16x16x32_bf16(A[s], Bu[t][s], au, 0, 0, 0);
          ag = __builtin_amdgcn_mfma_f32_16x16x32_bf16(A[s], Bg[t][s], ag, 0, 0, 0);
        }
        // D layout: col=lane&15 (feature), row=quad*4+r (node within sub-16)
#pragma unroll
        for (int r = 0; r < 4; ++r) {
          const float up = au[r] + bup[t];
          const float gt = ag[r] + bgt[t];
          gv[sub][t][r] = up * __builtin_amdgcn_rcpf(1.f + __expf(-gt));
        }
      }
    }

    // ---- in-register segment reduction ----
    // Each wave covers its own 32-feature strip for EVERY graph in the tile.
    // Lane (quad,l15) holds rows {sub*16+quad*4+r} of features
    // f0 = wave*32 + l15 (t=0) and f0+16 (t=1).
    {
      int i = 0;
      int sg = __shfl(sv, 0);
      while (sg < n_end && i < 63) {
        const int snext = __shfl(sv, i + 1);
        const int r0 = max(sg, n0) - n0;
        const int r1 = min(snext - 1, n_end) - n0;  // excludes graph's last node
        if (r1 > r0) {                               // wave-uniform branch
          float p0 = 0.f, p1 = 0.f;
#pragma unroll
          for (int sub = 0; sub < 4; ++sub) {
#pragma unroll
            for (int r = 0; r < 4; ++r) {
              const int row = sub * 16 + quad * 4 + r;
              const bool in = (row >= r0) && (row < r1);
              p0 += in ? gv[sub][0][r] : 0.f;
              p1 += in ? gv[sub][1][r] : 0.f;
            }
          }
          // butterfly across quads (lane^16, lane^32): all lanes get totals
          p0 += __shfl_xor(p0, 16); p0 += __shfl_xor(p0, 32);
          p1 += __shfl_xor(p1, 16); p1 += __shfl_xor(p1, 32);
          if (quad == 0)
            atomicAdd(&gsum[(size_t)(g0 + i) * 128 + wave * 32 + l15], p0);
          else if (quad == 1)
            atomicAdd(&gsum[(size_t)(g0 + i) * 128 + wave * 32 + 16 + l15], p1);
        }
        sg = snext;
        ++i;
      }
    }
    // no end-of-loop barrier: next iteration's bar_lds fences buffer reuse
    // (this wave's A-frag ds_reads drain in its own lgkmcnt(0) there; writes
    // to this buffer resume only after the FOLLOWING barrier, 2 tiles away)
  }
}

__global__ __launch_bounds__(256)
void stage2_kernel(const float* __restrict__ Wf, const float* __restrict__ bfv,
                   float* __restrict__ out, int G)
{
  __shared__ float Gsm[32 * 132];
  const int g0  = blockIdx.x * 32;
  const int tid = threadIdx.x;

  // stage this block's 32 graph_sums rows (then safe to overwrite in-place)
  for (int i = tid; i < 32 * 32; i += 256) {
    const int r = i >> 5;
    const int c = (i & 31) << 2;
    const int g = g0 + r;
    f32x4 v = {0.f, 0.f, 0.f, 0.f};
    if (g < G) v = *(const f32x4*)(out + (size_t)g * 128 + c);
    *(f32x4*)&Gsm[r * 132 + c] = v;
  }
  __syncthreads();

  const int fq  = tid & 31;
  const int f0  = fq << 2;            // 4 consecutive features
  const int grp = tid >> 5;           // 8 groups x 4 graphs
  float acc[4][4];
#pragma unroll
  for (int i = 0; i < 4; ++i)
#pragma unroll
    for (int j = 0; j < 4; ++j) acc[i][j] = 0.f;

#pragma unroll 4
  for (int k = 0; k < 128; ++k) {
    const f32x4 w = *(const f32x4*)(Wf + (size_t)k * 128 + f0);
#pragma unroll
    for (int i = 0; i < 4; ++i) {
      const float gv = Gsm[(grp * 4 + i) * 132 + k];
      acc[i][0] += gv * w[0];
      acc[i][1] += gv * w[1];
      acc[i][2] += gv * w[2];
      acc[i][3] += gv * w[3];
    }
  }

  const f32x4 bb = *(const f32x4*)(bfv + f0);
#pragma unroll
  for (int i = 0; i < 4; ++i) {
    const int g = g0 + grp * 4 + i;
    if (g < G) {
      f32x4 o = {acc[i][0] + bb[0], acc[i][1] + bb[1],
                 acc[i][2] + bb[2], acc[i][3] + bb[3]};
      *(f32x4*)(out + (size_t)g * 128 + f0) = o;
    }
  }
}

extern "C" void kernel_launch(void* const* d_in, const int* in_sizes, int n_in,
                              void* d_out, int out_size, void* d_ws, size_t ws_size,
                              hipStream_t stream)
{
  const float* X      = (const float*)d_in[0];
  const float* Wu     = (const float*)d_in[1];
  const float* bu     = (const float*)d_in[2];
  const float* Wg     = (const float*)d_in[3];
  const float* bg     = (const float*)d_in[4];
  const float* Wf     = (const float*)d_in[5];
  const float* bf_    = (const float*)d_in[6];
  const int*   starts = (const int*)d_in[7];

  const int G = in_sizes[7] - 1;
  const int V = in_sizes[0] / 128;
  const int ntiles = (V + 63) / 64;

  int*   tile_seg = (int*)d_ws;          // ntiles ints (~31 KB)
  float* gsum     = (float*)d_out;       // graph_sums accumulates in d_out

  hipMemsetAsync(d_out, 0, (size_t)G * 128 * sizeof(float), stream);
  tile_seg_kernel<<<(ntiles + 255) / 256, 256, 0, stream>>>(starts, tile_seg, ntiles, G);
  stage1_kernel<<<768, 256, 0, stream>>>(X, Wu, bu, Wg, bg, starts, tile_seg,
                                         gsum, V, G, ntiles);
  stage2_kernel<<<(G + 31) / 32, 256, 0, stream>>>(Wf, bf_, gsum, G);
}

// Round 5
// 399.144 us; speedup vs baseline: 1.2784x; 1.2784x over previous
//
#include <hip/hip_runtime.h>

// GraphFeaturesStackPad on MI355X.
// Stage 1: bf16 MFMA fused up/gate projection + sigmoid-gate + IN-REGISTER
//          segment-sum (atomicAdd into d_out as fp32 graph_sums accumulator).
// Stage 2: fp32 in-place GEMM graph_sums @ W_func + b_func.
// d_ws usage: ntiles ints (~31 KB) for per-tile first-graph index.
//
// R7 change vs R6 (counter-driven post-mortem):
//  - R6's VGPR_Count=84 (= floor(512/6)!) proves __launch_bounds__(256,3)
//    made the allocator target 6 waves/EU -> ~90 registers of live state
//    spilled to scratch. Evidence: FETCH_SIZE 481 MB (expected ~270),
//    WRITE_SIZE 203 MB (expected ~15) -- symmetric ~200 MB extra R+W =
//    scratch store/reload signature; VALUBusy 23%/MfmaUtil 6%/HBM 39%
//    all unsaturated = latency-bound on spill traffic.
//  - fix: __launch_bounds__(256, 2) (VGPR cap 256 >= ~175 demand, no spill),
//    grid 768 -> 512 (2 blocks/CU exact). LDS 36.9 KB x 2 = 74 KB/CU.
//  - keeps R6's in-register reduce (no Gs buffer, 1 barrier/tile) and R5's
//    unconditional clamped VMEM + lane-resident pipelined starts window.
// Prediction: VGPR ~170-210, FETCH ~270 MB, WRITE ~15 MB, stage1 <= 120 us.

typedef __bf16 bf16_t;
typedef bf16_t bf16x8 __attribute__((ext_vector_type(8)));
typedef float  f32x4  __attribute__((ext_vector_type(4)));

#define XS_STRIDE 144   // shorts; 288 B row = 72 dwords -> 4-way banks on b128

__device__ __forceinline__ unsigned short f2bf(float f) {
  unsigned int u = __float_as_uint(f);
  u += 0x7fffu + ((u >> 16) & 1u);   // RNE
  return (unsigned short)(u >> 16);
}

// LDS-only barrier: drains this wave's LDS ops then barriers; global loads
// (vmcnt) stay in flight, so the pipelined next-tile loads overlap compute.
__device__ __forceinline__ void bar_lds() {
  asm volatile("s_waitcnt lgkmcnt(0)\n\ts_barrier" ::: "memory");
}

__global__ void tile_seg_kernel(const int* __restrict__ starts,
                                int* __restrict__ tile_seg,
                                int ntiles, int G) {
  int i = blockIdx.x * blockDim.x + threadIdx.x;
  if (i >= ntiles) return;
  int n0 = i * 64;
  int lo = 0, hi = G - 1;            // largest g with starts[g] <= n0
  while (lo < hi) {
    int mid = (lo + hi + 1) >> 1;
    if (starts[mid] <= n0) lo = mid; else hi = mid - 1;
  }
  tile_seg[i] = lo;
}

__global__ __launch_bounds__(256, 2)
void stage1_kernel(const float* __restrict__ X,
                   const float* __restrict__ Wu, const float* __restrict__ bu,
                   const float* __restrict__ Wg, const float* __restrict__ bg,
                   const int* __restrict__ starts,
                   const int* __restrict__ tile_seg,
                   float* __restrict__ gsum, int V, int G, int ntiles)
{
  __shared__ unsigned short Xs[2][64 * XS_STRIDE]; // double-buffered bf16 tile (36.9 KB)

  const int tid  = threadIdx.x;
  const int lane = tid & 63;
  const int wave = tid >> 6;          // 4 waves; wave owns f-strip [wave*32, +32)
  const int quad = lane >> 4;
  const int l15  = lane & 15;

  // Persistent B fragments (W_up / W_gate) in registers, loaded once per block.
  // B-frag layout: lane holds B[k = s*32 + quad*8 + j][n = lane&15].
  bf16x8 Bu[2][4], Bg[2][4];
  float bup[2], bgt[2];
#pragma unroll
  for (int t = 0; t < 2; ++t) {
    const int f = wave * 32 + t * 16 + l15;
    bup[t] = bu[f];
    bgt[t] = bg[f];
#pragma unroll
    for (int s = 0; s < 4; ++s) {
      const int k0 = s * 32 + quad * 8;
      union { unsigned short us[8]; bf16x8 v; } a, b;
#pragma unroll
      for (int j = 0; j < 8; ++j) {
        a.us[j] = f2bf(Wu[(k0 + j) * 128 + f]);
        b.us[j] = f2bf(Wg[(k0 + j) * 128 + f]);
      }
      Bu[t][s] = a.v;
      Bg[t][s] = b.v;
    }
  }

  f32x4 ld[8];
  int tile = blockIdx.x;

  // preload first tile's data + window (clamped, unconditional)
  int g0v, sval;
  {
    const int t0 = min(tile, ntiles - 1);
    g0v  = tile_seg[t0];
    sval = starts[min(g0v + lane, G)];
    const int n0 = t0 * 64;
#pragma unroll
    for (int i = 0; i < 8; ++i) {
      const int flat = tid + i * 256;
      const int n = min(n0 + (flat >> 5), V - 1);
      const int k = (flat & 31) << 2;
      ld[i] = *(const f32x4*)(X + (size_t)n * 128 + k);
    }
  }

  int it = 0;
  for (; tile < ntiles; tile += gridDim.x, ++it) {
    const int n0    = tile * 64;
    const int n_end = min(n0 + 64, V);
    const int g0 = g0v;     // this tile's window (pipelined last iteration)
    const int sv = sval;
    unsigned short* xb = Xs[it & 1];

    // staged regs -> LDS as packed bf16 (8B ds_write); consumes the prefetch
#pragma unroll
    for (int i = 0; i < 8; ++i) {
      const int flat = tid + i * 256;
      const int n = flat >> 5;
      const int k = (flat & 31) << 2;
      const unsigned int p0 =
          (unsigned int)f2bf(ld[i][0]) | ((unsigned int)f2bf(ld[i][1]) << 16);
      const unsigned int p1 =
          (unsigned int)f2bf(ld[i][2]) | ((unsigned int)f2bf(ld[i][3]) << 16);
      *(uint2*)&xb[n * XS_STRIDE + k] = make_uint2(p0, p1);
    }

    // issue next tile's global loads NOW (clamped, unconditional); they stay
    // in flight through the lgkm-only barrier and the MFMA/reduce phases
    const int nextc = min(tile + (int)gridDim.x, ntiles - 1);
    {
      const int m0 = nextc * 64;
#pragma unroll
      for (int i = 0; i < 8; ++i) {
        const int flat = tid + i * 256;
        const int n = min(m0 + (flat >> 5), V - 1);
        const int k = (flat & 31) << 2;
        ld[i] = *(const f32x4*)(X + (size_t)n * 128 + k);
      }
    }
    // pipeline next tile's starts window (consumed next iteration's reduce)
    g0v  = tile_seg[nextc];
    sval = starts[min(g0v + lane, G)];

    bar_lds();   // ONE barrier per tile: Xs[it&1] writes visible; each wave's
                 // previous-tile A-frag reads already drained by its own lgkm

    // ---- MFMA phase + in-register epilogue: gv[sub][t][r] ----
    float gv[4][2][4];
#pragma unroll
    for (int sub = 0; sub < 4; ++sub) {
      bf16x8 A[4];
      const int nl = sub * 16 + l15;   // A-frag: A[m=lane&15][k=quad*8+j]
#pragma unroll
      for (int s = 0; s < 4; ++s)
        A[s] = *(const bf16x8*)&xb[nl * XS_STRIDE + s * 32 + quad * 8];
#pragma unroll
      for (int t = 0; t < 2; ++t) {
        f32x4 au = {0.f, 0.f, 0.f, 0.f};
        f32x4 ag = {0.f, 0.f, 0.f, 0.f};
#pragma unroll
        for (int s = 0; s < 4; ++s) {
          au = __builtin_amdgcn_mfma_f32_16x16x32_bf16(A[s], Bu[t][s], au, 0, 0, 0);
          ag = __builtin_amdgcn_mfma_f32_16x16x32_bf16(A[s], Bg[t][s], ag, 0, 0, 0);
        }
        // D layout: col=lane&15 (feature), row=quad*4+r (node within sub-16)
#pragma unroll
        for (int r = 0; r < 4; ++r) {
          const float up = au[r] + bup[t];
          const float gt = ag[r] + bgt[t];
          gv[sub][t][r] = up * __builtin_amdgcn_rcpf(1.f + __expf(-gt));
        }
      }
    }

    // ---- in-register segment reduction ----
    // Each wave covers its own 32-feature strip for EVERY graph in the tile.
    // Lane (quad,l15) holds rows {sub*16+quad*4+r} of features
    // f0 = wave*32 + l15 (t=0) and f0+16 (t=1).
    {
      int i = 0;
      int sg = __shfl(sv, 0);
      while (sg < n_end && i < 63) {
        const int snext = __shfl(sv, i + 1);
        const int r0 = max(sg, n0) - n0;
        const int r1 = min(snext - 1, n_end) - n0;  // excludes graph's last node
        if (r1 > r0) {                               // wave-uniform branch
          float p0 = 0.f, p1 = 0.f;
#pragma unroll
          for (int sub = 0; sub < 4; ++sub) {
#pragma unroll
            for (int r = 0; r < 4; ++r) {
              const int row = sub * 16 + quad * 4 + r;
              const bool in = (row >= r0) && (row < r1);
              p0 += in ? gv[sub][0][r] : 0.f;
              p1 += in ? gv[sub][1][r] : 0.f;
            }
          }
          // butterfly across quads (lane^16, lane^32): all lanes get totals
          p0 += __shfl_xor(p0, 16); p0 += __shfl_xor(p0, 32);
          p1 += __shfl_xor(p1, 16); p1 += __shfl_xor(p1, 32);
          if (quad == 0)
            atomicAdd(&gsum[(size_t)(g0 + i) * 128 + wave * 32 + l15], p0);
          else if (quad == 1)
            atomicAdd(&gsum[(size_t)(g0 + i) * 128 + wave * 32 + 16 + l15], p1);
        }
        sg = snext;
        ++i;
      }
    }
    // no end-of-loop barrier: next iteration's bar_lds fences buffer reuse
    // (this wave's A-frag ds_reads drain in its own lgkmcnt(0) there; writes
    // to this buffer resume only after the FOLLOWING barrier, 2 tiles away)
  }
}

__global__ __launch_bounds__(256)
void stage2_kernel(const float* __restrict__ Wf, const float* __restrict__ bfv,
                   float* __restrict__ out, int G)
{
  __shared__ float Gsm[32 * 132];
  const int g0  = blockIdx.x * 32;
  const int tid = threadIdx.x;

  // stage this block's 32 graph_sums rows (then safe to overwrite in-place)
  for (int i = tid; i < 32 * 32; i += 256) {
    const int r = i >> 5;
    const int c = (i & 31) << 2;
    const int g = g0 + r;
    f32x4 v = {0.f, 0.f, 0.f, 0.f};
    if (g < G) v = *(const f32x4*)(out + (size_t)g * 128 + c);
    *(f32x4*)&Gsm[r * 132 + c] = v;
  }
  __syncthreads();

  const int fq  = tid & 31;
  const int f0  = fq << 2;            // 4 consecutive features
  const int grp = tid >> 5;           // 8 groups x 4 graphs
  float acc[4][4];
#pragma unroll
  for (int i = 0; i < 4; ++i)
#pragma unroll
    for (int j = 0; j < 4; ++j) acc[i][j] = 0.f;

#pragma unroll 4
  for (int k = 0; k < 128; ++k) {
    const f32x4 w = *(const f32x4*)(Wf + (size_t)k * 128 + f0);
#pragma unroll
    for (int i = 0; i < 4; ++i) {
      const float gv = Gsm[(grp * 4 + i) * 132 + k];
      acc[i][0] += gv * w[0];
      acc[i][1] += gv * w[1];
      acc[i][2] += gv * w[2];
      acc[i][3] += gv * w[3];
    }
  }

  const f32x4 bb = *(const f32x4*)(bfv + f0);
#pragma unroll
  for (int i = 0; i < 4; ++i) {
    const int g = g0 + grp * 4 + i;
    if (g < G) {
      f32x4 o = {acc[i][0] + bb[0], acc[i][1] + bb[1],
                 acc[i][2] + bb[2], acc[i][3] + bb[3]};
      *(f32x4*)(out + (size_t)g * 128 + f0) = o;
    }
  }
}

extern "C" void kernel_launch(void* const* d_in, const int* in_sizes, int n_in,
                              void* d_out, int out_size, void* d_ws, size_t ws_size,
                              hipStream_t stream)
{
  const float* X      = (const float*)d_in[0];
  const float* Wu     = (const float*)d_in[1];
  const float* bu     = (const float*)d_in[2];
  const float* Wg     = (const float*)d_in[3];
  const float* bg     = (const float*)d_in[4];
  const float* Wf     = (const float*)d_in[5];
  const float* bf_    = (const float*)d_in[6];
  const int*   starts = (const int*)d_in[7];

  const int G = in_sizes[7] - 1;
  const int V = in_sizes[0] / 128;
  const int ntiles = (V + 63) / 64;

  int*   tile_seg = (int*)d_ws;          // ntiles ints (~31 KB)
  float* gsum     = (float*)d_out;       // graph_sums accumulates in d_out

  hipMemsetAsync(d_out, 0, (size_t)G * 128 * sizeof(float), stream);
  tile_seg_kernel<<<(ntiles + 255) / 256, 256, 0, stream>>>(starts, tile_seg, ntiles, G);
  stage1_kernel<<<512, 256, 0, stream>>>(X, Wu, bu, Wg, bg, starts, tile_seg,
                                         gsum, V, G, ntiles);
  stage2_kernel<<<(G + 31) / 32, 256, 0, stream>>>(Wf, bf_, gsum, G);
}